// Round 1
// baseline (797.331 us; speedup 1.0000x reference)
//
#include <hip/hip_runtime.h>

// AdaptSelfAttention: B=4, S=320, H=512, NH=8, DH=64
// Algebraic rewrite: B_D = (qv @ Wr_slice) . rpe  -> stream rpe once (839MB, HBM-bound)

#define NEGV (-1e15f)

typedef unsigned int u32;

__device__ __forceinline__ void gl_lds16(const float* g, float* l) {
  __builtin_amdgcn_global_load_lds(
      (const __attribute__((address_space(1))) u32*)(g),
      (__attribute__((address_space(3))) u32*)(l), 16, 0, 0);
}

__device__ __forceinline__ float dot4f(const float4 a, const float4 b) {
  return a.x*b.x + a.y*b.y + a.z*b.z + a.w*b.w;
}

// ---------------- K1: q/v projections -> qu, qv, valp ----------------
// grid (80 row-tiles, 4 col-tiles of 128, 2 which), 256 threads
__global__ __launch_bounds__(256) void k1_proj(
    const float* __restrict__ query, const float* __restrict__ value,
    const float* __restrict__ Wq, const float* __restrict__ bq,
    const float* __restrict__ Wv, const float* __restrict__ bv,
    const float* __restrict__ u, const float* __restrict__ v,
    float* __restrict__ qu, float* __restrict__ qv, float* __restrict__ valp)
{
  const int rt = blockIdx.x;      // 0..79 (16 rows each, rows = b*320+s)
  const int ct = blockIdx.y;      // 0..3 (128 cols each)
  const int which = blockIdx.z;   // 0: query, 1: value
  const int t = threadIdx.x;
  const int R0 = rt * 16;

  __shared__ float xs[16][516];

  const float* X = which ? value : query;
  const float* W = which ? Wv : Wq;
  const float* bias = which ? bv : bq;

  // stage 16x512 input rows
  #pragma unroll
  for (int j = 0; j < 8; ++j) {
    int f4 = t + 256 * j;              // 0..2047
    int row = f4 >> 7, c4 = f4 & 127;
    float4 xv = *reinterpret_cast<const float4*>(X + (size_t)(R0 + row) * 512 + c4 * 4);
    *reinterpret_cast<float4*>(&xs[row][c4 * 4]) = xv;
  }
  __syncthreads();

  const int r = t >> 4, clo = t & 15;
  #pragma unroll
  for (int sub = 0; sub < 2; ++sub) {
    const int cb = ct * 128 + sub * 64 + clo * 4;
    float a0 = 0.f, a1 = 0.f, a2 = 0.f, a3 = 0.f;
    const float* w0p = W + (size_t)(cb + 0) * 512;
    const float* w1p = W + (size_t)(cb + 1) * 512;
    const float* w2p = W + (size_t)(cb + 2) * 512;
    const float* w3p = W + (size_t)(cb + 3) * 512;
    #pragma unroll 2
    for (int m4 = 0; m4 < 128; ++m4) {
      float4 x4 = *reinterpret_cast<const float4*>(&xs[r][m4 * 4]);
      float4 w0 = *reinterpret_cast<const float4*>(w0p + m4 * 4);
      float4 w1 = *reinterpret_cast<const float4*>(w1p + m4 * 4);
      float4 w2 = *reinterpret_cast<const float4*>(w2p + m4 * 4);
      float4 w3 = *reinterpret_cast<const float4*>(w3p + m4 * 4);
      a0 += dot4f(x4, w0);
      a1 += dot4f(x4, w1);
      a2 += dot4f(x4, w2);
      a3 += dot4f(x4, w3);
    }
    a0 += bias[cb + 0]; a1 += bias[cb + 1]; a2 += bias[cb + 2]; a3 += bias[cb + 3];
    const size_t ob = (size_t)(R0 + r) * 512 + cb;
    if (which == 0) {
      float4 o1, o2;
      o1.x = a0 + u[cb + 0]; o1.y = a1 + u[cb + 1]; o1.z = a2 + u[cb + 2]; o1.w = a3 + u[cb + 3];
      o2.x = a0 + v[cb + 0]; o2.y = a1 + v[cb + 1]; o2.z = a2 + v[cb + 2]; o2.w = a3 + v[cb + 3];
      *reinterpret_cast<float4*>(qu + ob) = o1;
      *reinterpret_cast<float4*>(qv + ob) = o2;
    } else {
      float4 o; o.x = a0; o.y = a1; o.z = a2; o.w = a3;
      *reinterpret_cast<float4*>(valp + ob) = o;
    }
  }
}

// ---------------- K2: w[b,q,h,e] = qv_slice @ Wr_slice ; c[b,q,h] ----------------
// grid (80 row-tiles, 8 heads), 256 threads
__global__ __launch_bounds__(256) void k2_w(
    const float* __restrict__ qv, const float* __restrict__ Wr, const float* __restrict__ br,
    float* __restrict__ w_ws, float* __restrict__ c_ws)
{
  const int rt = blockIdx.x;   // 0..79
  const int h  = blockIdx.y;   // 0..7
  const int t = threadIdx.x;
  const int R0 = rt * 16;

  __shared__ float qs[16][68];
  {
    int row = t >> 4, d4 = t & 15;
    float4 x = *reinterpret_cast<const float4*>(qv + (size_t)(R0 + row) * 512 + h * 64 + d4 * 4);
    *reinterpret_cast<float4*>(&qs[row][d4 * 4]) = x;
  }
  __syncthreads();

  const int r = t >> 4, clo = t & 15;
  #pragma unroll
  for (int sub = 0; sub < 8; ++sub) {
    const int eb = sub * 64 + clo * 4;
    float4 acc; acc.x = 0.f; acc.y = 0.f; acc.z = 0.f; acc.w = 0.f;
    #pragma unroll 4
    for (int d = 0; d < 64; ++d) {
      float s = qs[r][d];
      float4 w4 = *reinterpret_cast<const float4*>(Wr + (size_t)(h * 64 + d) * 512 + eb);
      acc.x += s * w4.x; acc.y += s * w4.y; acc.z += s * w4.z; acc.w += s * w4.w;
    }
    *reinterpret_cast<float4*>(w_ws + (size_t)(R0 + r) * 4096 + h * 512 + eb) = acc;
  }
  if (t < 16) {
    float cs = 0.f;
    for (int d = 0; d < 64; ++d) cs += qs[t][d] * br[h * 64 + d];
    c_ws[(size_t)(R0 + t) * 8 + h] = cs;
  }
}

// ---------------- K4: fused scores (A_C + B_D + rand + c, mask) + softmax + PV ----------------
// grid (320 q, 4 b), 256 threads
__global__ __launch_bounds__(256, 2) void k4_attn(
    const float* __restrict__ rpe, const float* __restrict__ key,
    const float* __restrict__ rand_attn,
    const int* __restrict__ seq_len, const int* __restrict__ lex_num,
    const float* __restrict__ qu, const float* __restrict__ w_ws,
    const float* __restrict__ c_ws, const float* __restrict__ valp,
    float* __restrict__ out)
{
  const int q = blockIdx.x;   // 0..319
  const int b = blockIdx.y;   // 0..3
  const int t = threadIdx.x;
  const int wv = t >> 6, ln = t & 63;
  const int m = t & 31;       // e-slot within row group
  const int r = t >> 5;       // row group 0..7

  __shared__ float bufA[2][8][512];   // rpe tiles
  __shared__ float bufB[2][8][512];   // key tiles
  __shared__ float sc[8][320];
  __shared__ float cl[8];

  const size_t bq512 = ((size_t)b * 320 + q) * 512;
  const float* rpe_bq = rpe + ((size_t)b * 320 + q) * 320 * 512;
  const float* key_b  = key + (size_t)b * 320 * 512;

  // stage tile 0 (async)
  {
    #pragma unroll
    for (int jj = 0; jj < 4; ++jj) {
      const int chunk = jj * 256 + wv * 64;   // float4 index base (wave-uniform)
      gl_lds16(rpe_bq + (size_t)(chunk + ln) * 4, &bufA[0][0][0] + chunk * 4);
      gl_lds16(key_b  + (size_t)(chunk + ln) * 4, &bufB[0][0][0] + chunk * 4);
    }
  }

  if (t < 8) cl[t] = c_ws[((size_t)b * 320 + q) * 8 + t];
  const int len = seq_len[b] + lex_num[0];

  // register-cached w and qu fragments at this lane's fixed e-positions
  float4 wwc[4][8];
  float4 quc[4];
  const float* wbase = w_ws + ((size_t)b * 320 + q) * 4096;
  #pragma unroll
  for (int j = 0; j < 4; ++j) {
    const int p4 = 4 * (m + 32 * j);
    quc[j] = *reinterpret_cast<const float4*>(qu + bq512 + p4);
    #pragma unroll
    for (int h = 0; h < 8; ++h)
      wwc[j][h] = *reinterpret_cast<const float4*>(wbase + h * 512 + p4);
  }
  __syncthreads();   // cl visible (also drains tile-0 staging)

  // scores base: rand + c, masked
  for (int h = 0; h < 8; ++h) {
    for (int k = t; k < 320; k += 256) {
      float rv = rand_attn[((size_t)h * 320 + q) * 320 + k];
      sc[h][k] = (k < len) ? rv + cl[h] : NEGV;
    }
  }
  __syncthreads();

  // ------- main streaming loop over 40 tiles of 8 k-rows -------
  int cbuf = 0;
  for (int tile = 0; tile < 40; ++tile) {
    if (tile + 1 < 40) {
      const float* gA = rpe_bq + (size_t)(tile + 1) * 8 * 512;
      const float* gB = key_b  + (size_t)(tile + 1) * 8 * 512;
      const int nb = cbuf ^ 1;
      #pragma unroll
      for (int jj = 0; jj < 4; ++jj) {
        const int chunk = jj * 256 + wv * 64;
        gl_lds16(gA + (size_t)(chunk + ln) * 4, &bufA[nb][0][0] + chunk * 4);
        gl_lds16(gB + (size_t)(chunk + ln) * 4, &bufB[nb][0][0] + chunk * 4);
      }
    }

    float acc[8] = {0.f,0.f,0.f,0.f,0.f,0.f,0.f,0.f};
    float aac[4];
    #pragma unroll
    for (int j = 0; j < 4; ++j) {
      const int p4 = 4 * (m + 32 * j);
      const float4 r4 = *reinterpret_cast<const float4*>(&bufA[cbuf][r][p4]);
      const float4 k4 = *reinterpret_cast<const float4*>(&bufB[cbuf][r][p4]);
      #pragma unroll
      for (int h = 0; h < 8; ++h) acc[h] += dot4f(r4, wwc[j][h]);
      aac[j] = dot4f(k4, quc[j]);
    }

    // B_D: reduce across the 32 e-slot lanes
    #pragma unroll
    for (int h = 0; h < 8; ++h) {
      float vv = acc[h];
      vv += __shfl_xor(vv, 1, 32);
      vv += __shfl_xor(vv, 2, 32);
      vv += __shfl_xor(vv, 4, 32);
      vv += __shfl_xor(vv, 8, 32);
      vv += __shfl_xor(vv, 16, 32);
      acc[h] = vv;
    }
    // A_C: aac[j] belongs to head 2j (lanes m<16) / 2j+1 (lanes m>=16)
    #pragma unroll
    for (int j = 0; j < 4; ++j) {
      float vv = aac[j];
      vv += __shfl_xor(vv, 1, 16);
      vv += __shfl_xor(vv, 2, 16);
      vv += __shfl_xor(vv, 4, 16);
      vv += __shfl_xor(vv, 8, 16);
      float ov = __shfl_xor(vv, 16, 32);
      float lowv  = (m < 16) ? vv : ov;   // head 2j sum
      float highv = (m < 16) ? ov : vv;   // head 2j+1 sum
      acc[2 * j]     += lowv;
      acc[2 * j + 1] += highv;
    }

    const int kk = tile * 8 + r;
    if (m == 0) {
      #pragma unroll
      for (int h = 0; h < 8; ++h) sc[h][kk] += acc[h];
    }
    __syncthreads();
    cbuf ^= 1;
  }

  // ------- softmax per head row -------
  {
    const int h = t >> 5;
    float vals[10];
    float mx = -3.0e38f;
    #pragma unroll
    for (int i = 0; i < 10; ++i) { vals[i] = sc[h][m + 32 * i]; mx = fmaxf(mx, vals[i]); }
    mx = fmaxf(mx, __shfl_xor(mx, 1, 32));
    mx = fmaxf(mx, __shfl_xor(mx, 2, 32));
    mx = fmaxf(mx, __shfl_xor(mx, 4, 32));
    mx = fmaxf(mx, __shfl_xor(mx, 8, 32));
    mx = fmaxf(mx, __shfl_xor(mx, 16, 32));
    float s = 0.f;
    #pragma unroll
    for (int i = 0; i < 10; ++i) { vals[i] = __expf(vals[i] - mx); s += vals[i]; }
    s += __shfl_xor(s, 1, 32);
    s += __shfl_xor(s, 2, 32);
    s += __shfl_xor(s, 4, 32);
    s += __shfl_xor(s, 8, 32);
    s += __shfl_xor(s, 16, 32);
    const float inv = 1.0f / s;
    #pragma unroll
    for (int i = 0; i < 10; ++i) sc[h][m + 32 * i] = vals[i] * inv;
  }
  __syncthreads();

  // ------- PV: out[h*64+d] = sum_k p[h][k] * valp[b,k,h*64+d] -------
  {
    const int h = t >> 5, d2 = m;   // d = 2*d2
    float2 a0; a0.x = 0.f; a0.y = 0.f;
    float2 a1; a1.x = 0.f; a1.y = 0.f;
    const float* vb = valp + (size_t)b * 320 * 512 + h * 64 + d2 * 2;
    #pragma unroll 4
    for (int k = 0; k < 320; k += 2) {
      float p0 = sc[h][k], p1 = sc[h][k + 1];
      float2 v0 = *reinterpret_cast<const float2*>(vb + (size_t)k * 512);
      float2 v1 = *reinterpret_cast<const float2*>(vb + (size_t)(k + 1) * 512);
      a0.x += p0 * v0.x; a0.y += p0 * v0.y;
      a1.x += p1 * v1.x; a1.y += p1 * v1.y;
    }
    float2 o; o.x = a0.x + a1.x; o.y = a0.y + a1.y;
    *reinterpret_cast<float2*>(out + bq512 + h * 64 + d2 * 2) = o;
  }
}

extern "C" void kernel_launch(void* const* d_in, const int* in_sizes, int n_in,
                              void* d_out, int out_size, void* d_ws, size_t ws_size,
                              hipStream_t stream) {
  const float* query = (const float*)d_in[0];
  const float* key   = (const float*)d_in[1];
  const float* value = (const float*)d_in[2];
  const float* rpe   = (const float*)d_in[3];
  const int*   seq_len = (const int*)d_in[4];
  const int*   lex_num = (const int*)d_in[5];
  const float* Wq = (const float*)d_in[6];
  const float* bq = (const float*)d_in[7];
  const float* Wv = (const float*)d_in[8];
  const float* bv = (const float*)d_in[9];
  const float* Wr = (const float*)d_in[10];
  const float* br = (const float*)d_in[11];
  const float* u  = (const float*)d_in[12];
  const float* v  = (const float*)d_in[13];
  const float* rnd = (const float*)d_in[14];

  float* out = (float*)d_out;
  float* ws = (float*)d_ws;
  float* qu   = ws;                 // 655360
  float* qv   = ws + 655360;        // 655360
  float* valp = ws + 1310720;       // 655360
  float* w_ws = ws + 1966080;       // 5242880
  float* c_ws = ws + 7208960;       // 10240

  k1_proj<<<dim3(80, 4, 2), 256, 0, stream>>>(query, value, Wq, bq, Wv, bv, u, v, qu, qv, valp);
  k2_w<<<dim3(80, 8), 256, 0, stream>>>(qv, Wr, br, w_ws, c_ws);
  k4_attn<<<dim3(320, 4), 256, 0, stream>>>(rpe, key, rnd, seq_len, lex_num, qu, w_ws, c_ws, valp, out);
}

// Round 2
// 688.562 us; speedup vs baseline: 1.1580x; 1.1580x over previous
//
#include <hip/hip_runtime.h>

// AdaptSelfAttention: B=4, S=320, H=512, NH=8, DH=64
// B_D = (qv @ Wr_slice) . rpe  -> stream rpe once (839MB, HBM-bound)
// k1: q/v projections; k2: w[b,q,h,e], c[b,q,h]; k3: score base = A_C+rand+c;
// k4: stream rpe, add B_D, softmax, PV.

#define NEGV (-1e15f)

typedef unsigned int u32;

__device__ __forceinline__ void gl_lds16(const float* g, float* l) {
  __builtin_amdgcn_global_load_lds(
      (const __attribute__((address_space(1))) u32*)(g),
      (__attribute__((address_space(3))) u32*)(l), 16, 0, 0);
}

__device__ __forceinline__ float dot4f(const float4 a, const float4 b) {
  return a.x*b.x + a.y*b.y + a.z*b.z + a.w*b.w;
}

// ---------------- K1: q/v projections -> qu, qv, valp ----------------
__global__ __launch_bounds__(256) void k1_proj(
    const float* __restrict__ query, const float* __restrict__ value,
    const float* __restrict__ Wq, const float* __restrict__ bq,
    const float* __restrict__ Wv, const float* __restrict__ bv,
    const float* __restrict__ u, const float* __restrict__ v,
    float* __restrict__ qu, float* __restrict__ qv, float* __restrict__ valp)
{
  const int rt = blockIdx.x;      // 0..79 (16 rows)
  const int ct = blockIdx.y;      // 0..3 (128 cols)
  const int which = blockIdx.z;   // 0: query, 1: value
  const int t = threadIdx.x;
  const int R0 = rt * 16;

  __shared__ float xs[16][516];

  const float* X = which ? value : query;
  const float* W = which ? Wv : Wq;
  const float* bias = which ? bv : bq;

  #pragma unroll
  for (int j = 0; j < 8; ++j) {
    int f4 = t + 256 * j;
    int row = f4 >> 7, c4 = f4 & 127;
    float4 xv = *reinterpret_cast<const float4*>(X + (size_t)(R0 + row) * 512 + c4 * 4);
    *reinterpret_cast<float4*>(&xs[row][c4 * 4]) = xv;
  }
  __syncthreads();

  const int r = t >> 4, clo = t & 15;
  #pragma unroll
  for (int sub = 0; sub < 2; ++sub) {
    const int cb = ct * 128 + sub * 64 + clo * 4;
    float a0 = 0.f, a1 = 0.f, a2 = 0.f, a3 = 0.f;
    const float* w0p = W + (size_t)(cb + 0) * 512;
    const float* w1p = W + (size_t)(cb + 1) * 512;
    const float* w2p = W + (size_t)(cb + 2) * 512;
    const float* w3p = W + (size_t)(cb + 3) * 512;
    #pragma unroll 2
    for (int m4 = 0; m4 < 128; ++m4) {
      float4 x4 = *reinterpret_cast<const float4*>(&xs[r][m4 * 4]);
      float4 w0 = *reinterpret_cast<const float4*>(w0p + m4 * 4);
      float4 w1 = *reinterpret_cast<const float4*>(w1p + m4 * 4);
      float4 w2 = *reinterpret_cast<const float4*>(w2p + m4 * 4);
      float4 w3 = *reinterpret_cast<const float4*>(w3p + m4 * 4);
      a0 += dot4f(x4, w0);
      a1 += dot4f(x4, w1);
      a2 += dot4f(x4, w2);
      a3 += dot4f(x4, w3);
    }
    a0 += bias[cb + 0]; a1 += bias[cb + 1]; a2 += bias[cb + 2]; a3 += bias[cb + 3];
    const size_t ob = (size_t)(R0 + r) * 512 + cb;
    if (which == 0) {
      float4 o1, o2;
      o1.x = a0 + u[cb + 0]; o1.y = a1 + u[cb + 1]; o1.z = a2 + u[cb + 2]; o1.w = a3 + u[cb + 3];
      o2.x = a0 + v[cb + 0]; o2.y = a1 + v[cb + 1]; o2.z = a2 + v[cb + 2]; o2.w = a3 + v[cb + 3];
      *reinterpret_cast<float4*>(qu + ob) = o1;
      *reinterpret_cast<float4*>(qv + ob) = o2;
    } else {
      float4 o; o.x = a0; o.y = a1; o.z = a2; o.w = a3;
      *reinterpret_cast<float4*>(valp + ob) = o;
    }
  }
}

// ---------------- K2: w[b,q,h,e] = qv_slice @ Wr_slice ; c[b,q,h] ----------------
__global__ __launch_bounds__(256) void k2_w(
    const float* __restrict__ qv, const float* __restrict__ Wr, const float* __restrict__ br,
    float* __restrict__ w_ws, float* __restrict__ c_ws)
{
  const int rt = blockIdx.x;   // 0..79
  const int h  = blockIdx.y;   // 0..7
  const int t = threadIdx.x;
  const int R0 = rt * 16;

  __shared__ float qs[16][68];
  {
    int row = t >> 4, d4 = t & 15;
    float4 x = *reinterpret_cast<const float4*>(qv + (size_t)(R0 + row) * 512 + h * 64 + d4 * 4);
    *reinterpret_cast<float4*>(&qs[row][d4 * 4]) = x;
  }
  __syncthreads();

  const int r = t >> 4, clo = t & 15;
  #pragma unroll
  for (int sub = 0; sub < 8; ++sub) {
    const int eb = sub * 64 + clo * 4;
    float4 acc; acc.x = 0.f; acc.y = 0.f; acc.z = 0.f; acc.w = 0.f;
    #pragma unroll 4
    for (int d = 0; d < 64; ++d) {
      float s = qs[r][d];
      float4 w4 = *reinterpret_cast<const float4*>(Wr + (size_t)(h * 64 + d) * 512 + eb);
      acc.x += s * w4.x; acc.y += s * w4.y; acc.z += s * w4.z; acc.w += s * w4.w;
    }
    *reinterpret_cast<float4*>(w_ws + (size_t)(R0 + r) * 4096 + h * 512 + eb) = acc;
  }
  if (t < 16) {
    float cs = 0.f;
    for (int d = 0; d < 64; ++d) cs += qs[t][d] * br[h * 64 + d];
    c_ws[(size_t)(R0 + t) * 8 + h] = cs;
  }
}

// ---------------- K3: score base = A_C + rand + c -> sc_ws[b,q,h,k] ----------------
// grid (20 qtiles, 8 h, 4 b), 320 threads (thread = k)
__global__ __launch_bounds__(320) void k3_ac(
    const float* __restrict__ qu, const float* __restrict__ key,
    const float* __restrict__ rand_attn, const float* __restrict__ c_ws,
    float* __restrict__ sc_ws)
{
  const int qt = blockIdx.x;
  const int h  = blockIdx.y;
  const int b  = blockIdx.z;
  const int t  = threadIdx.x;   // k
  const int q0 = qt * 16;

  const float* kr = key + ((size_t)b * 320 + t) * 512 + h * 64;
  float4 krow[16];
  #pragma unroll
  for (int i = 0; i < 16; ++i) krow[i] = *reinterpret_cast<const float4*>(kr + i * 4);

  float acc[16];
  #pragma unroll
  for (int qi = 0; qi < 16; ++qi) {
    const float* qrow = qu + ((size_t)b * 320 + q0 + qi) * 512 + h * 64;  // block-uniform
    float a = 0.f;
    #pragma unroll
    for (int i = 0; i < 16; ++i) {
      float4 q4 = *reinterpret_cast<const float4*>(qrow + i * 4);
      a += dot4f(q4, krow[i]);
    }
    acc[qi] = a;
  }
  #pragma unroll
  for (int qi = 0; qi < 16; ++qi) {
    const int q = q0 + qi;
    float r = rand_attn[((size_t)h * 320 + q) * 320 + t];
    float c = c_ws[((size_t)b * 320 + q) * 8 + h];
    sc_ws[(((size_t)b * 320 + q) * 8 + h) * 320 + t] = acc[qi] + r + c;
  }
}

// ---------------- K4: stream rpe, B_D, softmax, PV ----------------
// grid (320 q, 4 b), 256 threads. Wave w owns heads {2w,2w+1}.
// Tile = 16 k-rows (32KB), double-buffered, XOR-swizzled LDS (T2/G4).
__global__ __launch_bounds__(256, 2) void k4_attn(
    const float* __restrict__ rpe,
    const int* __restrict__ seq_len, const int* __restrict__ lex_num,
    const float* __restrict__ w_ws, const float* __restrict__ sc_ws,
    const float* __restrict__ valp,
    float* __restrict__ out)
{
  const int q = blockIdx.x;
  const int b = blockIdx.y;
  const int t = threadIdx.x;
  const int w = t >> 6;          // wave 0..3 -> heads 2w, 2w+1
  const int lane = t & 63;
  const int row8 = lane >> 3;    // 0..7
  const int chunk = lane & 7;    // 64-e chunk
  const int rc = (row8 ^ chunk) & 7;

  __shared__ float bufA[2][16][512];   // 64 KB, swizzled storage
  __shared__ float sc[8][320];

  const size_t bq = (size_t)b * 320 + q;
  const float* rpe_bq = rpe + bq * 320 * 512;

  // staging source offsets (inverse swizzle), 8 per thread
  int g[8];
  #pragma unroll
  for (int j = 0; j < 8; ++j) {
    int o = (w * 8 + j) * 1024 + lane * 16;   // dest byte in 32KB tile
    int row = o >> 11;
    int ch  = (o >> 8) & 7;
    int win = (o >> 7) & 1;
    int slot = (o >> 4) & 7;
    int i = win * 8 + (slot ^ ((row ^ ch) & 7));
    g[j] = row * 512 + (ch * 16 + i) * 4;     // source float offset
  }

  // stage tile 0
  #pragma unroll
  for (int j = 0; j < 8; ++j)
    gl_lds16(rpe_bq + g[j], &bufA[0][0][0] + (w * 8 + j) * 256);

  // w fragments: 2 heads x 16 float4 (this lane's 64-e chunk)
  const int h0 = 2 * w, h1 = 2 * w + 1;
  const float* wb0 = w_ws + bq * 4096 + (size_t)h0 * 512 + chunk * 64;
  const float* wb1 = w_ws + bq * 4096 + (size_t)h1 * 512 + chunk * 64;
  float4 wc0[16], wc1[16];
  #pragma unroll
  for (int i = 0; i < 16; ++i) {
    wc0[i] = *reinterpret_cast<const float4*>(wb0 + i * 4);
    wc1[i] = *reinterpret_cast<const float4*>(wb1 + i * 4);
  }

  // scores base from sc_ws, masked
  const int len = seq_len[b] + lex_num[0];
  const float* scb = sc_ws + bq * 8 * 320;
  for (int h = 0; h < 8; ++h) {
    for (int k = t; k < 320; k += 256) {
      float vv = scb[h * 320 + k];
      sc[h][k] = (k < len) ? vv : NEGV;
    }
  }
  __syncthreads();   // tile 0 staged (vmcnt drain) + sc visible

  const int Cb0 = row8 * 2048 + chunk * 256 + rc * 16;
  const char* bufbase = reinterpret_cast<const char*>(&bufA[0][0][0]);

  int cb = 0;
  for (int tile = 0; tile < 20; ++tile) {
    if (tile + 1 < 20) {
      const float* src = rpe_bq + (size_t)(tile + 1) * 8192;
      float* dst = &bufA[cb ^ 1][0][0];
      #pragma unroll
      for (int j = 0; j < 8; ++j)
        gl_lds16(src + g[j], dst + (w * 8 + j) * 256);
    }

    const char* bufc = bufbase + cb * 32768;
    #pragma unroll
    for (int pass = 0; pass < 2; ++pass) {
      const int C = Cb0 + pass * 16384;
      float a0 = 0.f, a1 = 0.f;
      #pragma unroll
      for (int i = 0; i < 16; ++i) {
        const float4 r4 = *reinterpret_cast<const float4*>(bufc + (C ^ (i << 4)));
        a0 += dot4f(r4, wc0[i]);
        a1 += dot4f(r4, wc1[i]);
      }
      a0 += __shfl_xor(a0, 1, 8);
      a0 += __shfl_xor(a0, 2, 8);
      a0 += __shfl_xor(a0, 4, 8);
      a1 += __shfl_xor(a1, 1, 8);
      a1 += __shfl_xor(a1, 2, 8);
      a1 += __shfl_xor(a1, 4, 8);
      if (chunk == 0) {
        const int kk = tile * 16 + pass * 8 + row8;
        sc[h0][kk] += a0;
        sc[h1][kk] += a1;
      }
    }
    __syncthreads();
    cb ^= 1;
  }

  // ------- softmax per head row -------
  {
    const int h = t >> 5, m = t & 31;
    float vals[10];
    float mx = -3.0e38f;
    #pragma unroll
    for (int i = 0; i < 10; ++i) { vals[i] = sc[h][m + 32 * i]; mx = fmaxf(mx, vals[i]); }
    mx = fmaxf(mx, __shfl_xor(mx, 1, 32));
    mx = fmaxf(mx, __shfl_xor(mx, 2, 32));
    mx = fmaxf(mx, __shfl_xor(mx, 4, 32));
    mx = fmaxf(mx, __shfl_xor(mx, 8, 32));
    mx = fmaxf(mx, __shfl_xor(mx, 16, 32));
    float s = 0.f;
    #pragma unroll
    for (int i = 0; i < 10; ++i) { vals[i] = __expf(vals[i] - mx); s += vals[i]; }
    s += __shfl_xor(s, 1, 32);
    s += __shfl_xor(s, 2, 32);
    s += __shfl_xor(s, 4, 32);
    s += __shfl_xor(s, 8, 32);
    s += __shfl_xor(s, 16, 32);
    const float inv = 1.0f / s;
    #pragma unroll
    for (int i = 0; i < 10; ++i) sc[h][m + 32 * i] = vals[i] * inv;
  }
  __syncthreads();

  // ------- PV -------
  {
    const int h = t >> 5, d2 = t & 31;
    float2 a0; a0.x = 0.f; a0.y = 0.f;
    float2 a1; a1.x = 0.f; a1.y = 0.f;
    const float* vb = valp + (size_t)b * 320 * 512 + h * 64 + d2 * 2;
    #pragma unroll 4
    for (int k = 0; k < 320; k += 2) {
      float p0 = sc[h][k], p1 = sc[h][k + 1];
      float2 v0 = *reinterpret_cast<const float2*>(vb + (size_t)k * 512);
      float2 v1 = *reinterpret_cast<const float2*>(vb + (size_t)(k + 1) * 512);
      a0.x += p0 * v0.x; a0.y += p0 * v0.y;
      a1.x += p1 * v1.x; a1.y += p1 * v1.y;
    }
    float2 o; o.x = a0.x + a1.x; o.y = a0.y + a1.y;
    *reinterpret_cast<float2*>(out + bq * 512 + h * 64 + d2 * 2) = o;
  }
}

extern "C" void kernel_launch(void* const* d_in, const int* in_sizes, int n_in,
                              void* d_out, int out_size, void* d_ws, size_t ws_size,
                              hipStream_t stream) {
  const float* query = (const float*)d_in[0];
  const float* key   = (const float*)d_in[1];
  const float* value = (const float*)d_in[2];
  const float* rpe   = (const float*)d_in[3];
  const int*   seq_len = (const int*)d_in[4];
  const int*   lex_num = (const int*)d_in[5];
  const float* Wq = (const float*)d_in[6];
  const float* bq = (const float*)d_in[7];
  const float* Wv = (const float*)d_in[8];
  const float* bv = (const float*)d_in[9];
  const float* Wr = (const float*)d_in[10];
  const float* br = (const float*)d_in[11];
  const float* u  = (const float*)d_in[12];
  const float* v  = (const float*)d_in[13];
  const float* rnd = (const float*)d_in[14];

  float* out = (float*)d_out;
  float* ws = (float*)d_ws;
  float* qu    = ws;                 // 655360
  float* qv    = ws + 655360;        // 655360
  float* valp  = ws + 1310720;       // 655360
  float* w_ws  = ws + 1966080;       // 5242880
  float* c_ws  = ws + 7208960;       // 10240
  float* sc_ws = ws + 7219200;       // 3276800

  k1_proj<<<dim3(80, 4, 2), 256, 0, stream>>>(query, value, Wq, bq, Wv, bv, u, v, qu, qv, valp);
  k2_w<<<dim3(80, 8), 256, 0, stream>>>(qv, Wr, br, w_ws, c_ws);
  k3_ac<<<dim3(20, 8, 4), 320, 0, stream>>>(qu, key, rnd, c_ws, sc_ws);
  k4_attn<<<dim3(320, 4), 256, 0, stream>>>(rpe, seq_len, lex_num, w_ws, sc_ws, valp, out);
}

// Round 3
// 684.511 us; speedup vs baseline: 1.1648x; 1.0059x over previous
//
#include <hip/hip_runtime.h>

// AdaptSelfAttention: B=4, S=320, H=512, NH=8, DH=64
// B_D = (qv @ Wr_slice) . rpe  -> stream rpe once (839MB, HBM-bound)
// k1: q/v projections -> qu, qv, valp
// k4: prologue (w = qv@Wr into LDS scratch; A_C+rand+c+mask into sc) then
//     stream rpe (swizzled gl_lds, double-buffered), B_D, softmax, PV.

#define NEGV (-1e15f)

typedef unsigned int u32;

__device__ __forceinline__ void gl_lds16(const float* g, float* l) {
  __builtin_amdgcn_global_load_lds(
      (const __attribute__((address_space(1))) u32*)(g),
      (__attribute__((address_space(3))) u32*)(l), 16, 0, 0);
}

__device__ __forceinline__ float dot4f(const float4 a, const float4 b) {
  return a.x*b.x + a.y*b.y + a.z*b.z + a.w*b.w;
}

// ---------------- K1: q/v projections -> qu, qv, valp ----------------
__global__ __launch_bounds__(256) void k1_proj(
    const float* __restrict__ query, const float* __restrict__ value,
    const float* __restrict__ Wq, const float* __restrict__ bq,
    const float* __restrict__ Wv, const float* __restrict__ bv,
    const float* __restrict__ u, const float* __restrict__ v,
    float* __restrict__ qu, float* __restrict__ qv, float* __restrict__ valp)
{
  const int rt = blockIdx.x;      // 0..79 (16 rows)
  const int ct = blockIdx.y;      // 0..3 (128 cols)
  const int which = blockIdx.z;   // 0: query, 1: value
  const int t = threadIdx.x;
  const int R0 = rt * 16;

  __shared__ float xs[16][516];

  const float* X = which ? value : query;
  const float* W = which ? Wv : Wq;
  const float* bias = which ? bv : bq;

  #pragma unroll
  for (int j = 0; j < 8; ++j) {
    int f4 = t + 256 * j;
    int row = f4 >> 7, c4 = f4 & 127;
    float4 xv = *reinterpret_cast<const float4*>(X + (size_t)(R0 + row) * 512 + c4 * 4);
    *reinterpret_cast<float4*>(&xs[row][c4 * 4]) = xv;
  }
  __syncthreads();

  const int r = t >> 4, clo = t & 15;
  #pragma unroll
  for (int sub = 0; sub < 2; ++sub) {
    const int cb = ct * 128 + sub * 64 + clo * 4;
    float a0 = 0.f, a1 = 0.f, a2 = 0.f, a3 = 0.f;
    const float* w0p = W + (size_t)(cb + 0) * 512;
    const float* w1p = W + (size_t)(cb + 1) * 512;
    const float* w2p = W + (size_t)(cb + 2) * 512;
    const float* w3p = W + (size_t)(cb + 3) * 512;
    #pragma unroll 2
    for (int m4 = 0; m4 < 128; ++m4) {
      float4 x4 = *reinterpret_cast<const float4*>(&xs[r][m4 * 4]);
      float4 w0 = *reinterpret_cast<const float4*>(w0p + m4 * 4);
      float4 w1 = *reinterpret_cast<const float4*>(w1p + m4 * 4);
      float4 w2 = *reinterpret_cast<const float4*>(w2p + m4 * 4);
      float4 w3 = *reinterpret_cast<const float4*>(w3p + m4 * 4);
      a0 += dot4f(x4, w0);
      a1 += dot4f(x4, w1);
      a2 += dot4f(x4, w2);
      a3 += dot4f(x4, w3);
    }
    a0 += bias[cb + 0]; a1 += bias[cb + 1]; a2 += bias[cb + 2]; a3 += bias[cb + 3];
    const size_t ob = (size_t)(R0 + r) * 512 + cb;
    if (which == 0) {
      float4 o1, o2;
      o1.x = a0 + u[cb + 0]; o1.y = a1 + u[cb + 1]; o1.z = a2 + u[cb + 2]; o1.w = a3 + u[cb + 3];
      o2.x = a0 + v[cb + 0]; o2.y = a1 + v[cb + 1]; o2.z = a2 + v[cb + 2]; o2.w = a3 + v[cb + 3];
      *reinterpret_cast<float4*>(qu + ob) = o1;
      *reinterpret_cast<float4*>(qv + ob) = o2;
    } else {
      float4 o; o.x = a0; o.y = a1; o.z = a2; o.w = a3;
      *reinterpret_cast<float4*>(valp + ob) = o;
    }
  }
}

// ---------------- K4: fused prologue + rpe stream + softmax + PV ----------------
// grid (320 q, 4 b), 256 threads. Wave w owns heads {2w,2w+1}.
// Tile = 16 k-rows (32KB), double-buffered, XOR-swizzled LDS.
__global__ __launch_bounds__(256, 2) void k4_attn(
    const float* __restrict__ rpe, const float* __restrict__ key,
    const float* __restrict__ Wr, const float* __restrict__ br,
    const float* __restrict__ rand_attn,
    const int* __restrict__ seq_len, const int* __restrict__ lex_num,
    const float* __restrict__ qu, const float* __restrict__ qv,
    const float* __restrict__ valp,
    float* __restrict__ out)
{
  const int q = blockIdx.x;
  const int b = blockIdx.y;
  const int t = threadIdx.x;
  const int w = t >> 6;          // wave 0..3 -> heads 2w, 2w+1
  const int lane = t & 63;
  const int row8 = lane >> 3;    // 0..7
  const int chunk = lane & 7;    // 64-e chunk

  __shared__ float bufA[2][16][512];   // 64 KB, swizzled storage
  __shared__ float sc[8][320];

  const size_t bq = (size_t)b * 320 + q;
  const float* rpe_bq = rpe + bq * 320 * 512;
  float* wscr = &bufA[1][0][0];        // 16 KB scratch for w[8][512] (prologue only)

  // staging source offsets (inverse swizzle), 8 per thread
  int g[8];
  #pragma unroll
  for (int j = 0; j < 8; ++j) {
    int o = (w * 8 + j) * 1024 + lane * 16;   // dest byte in 32KB tile
    int row = o >> 11;
    int ch  = (o >> 8) & 7;
    int win = (o >> 7) & 1;
    int slot = (o >> 4) & 7;
    int i = win * 8 + (slot ^ ((row ^ ch) & 7));
    g[j] = row * 512 + (ch * 16 + i) * 4;     // source float offset
  }

  // stage tile 0 (async; does not touch bufA[1])
  #pragma unroll
  for (int j = 0; j < 8; ++j)
    gl_lds16(rpe_bq + g[j], &bufA[0][0][0] + (w * 8 + j) * 256);

  // ---------------- prologue (hidden under tile-0 staging) ----------------
  const int hh = t >> 5, m = t & 31;           // thread -> (head, slot)
  const float* qv_row = qv + bq * 512 + hh * 64;

  // (1) w[hh][m*16 .. m*16+15] = sum_d qv_row[d] * Wr[hh*64+d][e]
  {
    float4 a4[4];
    #pragma unroll
    for (int ii = 0; ii < 4; ++ii) { a4[ii].x = 0.f; a4[ii].y = 0.f; a4[ii].z = 0.f; a4[ii].w = 0.f; }
    const float* wrb = Wr + (size_t)(hh * 64) * 512 + m * 16;
    #pragma unroll 4
    for (int d = 0; d < 64; ++d) {
      float s = qv_row[d];
      const float4* w4 = reinterpret_cast<const float4*>(wrb + (size_t)d * 512);
      #pragma unroll
      for (int ii = 0; ii < 4; ++ii) {
        a4[ii].x += s * w4[ii].x; a4[ii].y += s * w4[ii].y;
        a4[ii].z += s * w4[ii].z; a4[ii].w += s * w4[ii].w;
      }
    }
    #pragma unroll
    for (int ii = 0; ii < 4; ++ii)
      *reinterpret_cast<float4*>(wscr + hh * 512 + m * 16 + ii * 4) = a4[ii];
  }

  // (2) c = qv_row . br_slice (redundant across the 32 threads of head hh)
  float c = 0.f;
  #pragma unroll 8
  for (int d = 0; d < 64; ++d) c += qv_row[d] * br[hh * 64 + d];

  // (3) A_C + rand + c, masked -> sc[hh][k]
  const int len = seq_len[b] + lex_num[0];
  {
    const float* qup = qu + bq * 512 + hh * 64;
    const float* keyb = key + (size_t)b * 320 * 512 + hh * 64;
    const float* rnd_hq = rand_attn + ((size_t)hh * 320 + q) * 320;
    #pragma unroll
    for (int i = 0; i < 10; ++i) {
      const int k = m + 32 * i;
      float val;
      if (k < len) {
        const float* kr = keyb + (size_t)k * 512;
        float a = 0.f;
        #pragma unroll
        for (int ii = 0; ii < 16; ++ii)
          a += dot4f(reinterpret_cast<const float4*>(qup)[ii],
                     reinterpret_cast<const float4*>(kr)[ii]);
        val = a + rnd_hq[k] + c;
      } else {
        val = NEGV;
      }
      sc[hh][k] = val;
    }
  }
  __syncthreads();   // wscr + sc visible; tile-0 staged (vmcnt drain)

  // (4) read w fragments: 2 heads x 16 float4 (this lane's 64-e chunk)
  const int h0 = 2 * w, h1 = 2 * w + 1;
  float4 wc0[16], wc1[16];
  #pragma unroll
  for (int i = 0; i < 16; ++i) {
    wc0[i] = *reinterpret_cast<const float4*>(wscr + h0 * 512 + chunk * 64 + i * 4);
    wc1[i] = *reinterpret_cast<const float4*>(wscr + h1 * 512 + chunk * 64 + i * 4);
  }
  __syncthreads();   // all w reads done before tile-1 staging overwrites bufA[1]

  // ---------------- main streaming loop over 20 tiles of 16 k-rows ----------------
  const int rc = (row8 ^ chunk) & 7;
  const int Cb0 = row8 * 2048 + chunk * 256 + rc * 16;
  const char* bufbase = reinterpret_cast<const char*>(&bufA[0][0][0]);

  int cb = 0;
  for (int tile = 0; tile < 20; ++tile) {
    if (tile + 1 < 20) {
      const float* src = rpe_bq + (size_t)(tile + 1) * 8192;
      float* dst = &bufA[cb ^ 1][0][0];
      #pragma unroll
      for (int j = 0; j < 8; ++j)
        gl_lds16(src + g[j], dst + (w * 8 + j) * 256);
    }

    const char* bufc = bufbase + cb * 32768;
    #pragma unroll
    for (int pass = 0; pass < 2; ++pass) {
      const int C = Cb0 + pass * 16384;
      float a0 = 0.f, a1 = 0.f;
      #pragma unroll
      for (int i = 0; i < 16; ++i) {
        const float4 r4 = *reinterpret_cast<const float4*>(bufc + (C ^ (i << 4)));
        a0 += dot4f(r4, wc0[i]);
        a1 += dot4f(r4, wc1[i]);
      }
      a0 += __shfl_xor(a0, 1, 8);
      a0 += __shfl_xor(a0, 2, 8);
      a0 += __shfl_xor(a0, 4, 8);
      a1 += __shfl_xor(a1, 1, 8);
      a1 += __shfl_xor(a1, 2, 8);
      a1 += __shfl_xor(a1, 4, 8);
      if (chunk == 0) {
        const int kk = tile * 16 + pass * 8 + row8;
        sc[h0][kk] += a0;
        sc[h1][kk] += a1;
      }
    }
    __syncthreads();
    cb ^= 1;
  }

  // ------- softmax per head row -------
  {
    float vals[10];
    float mx = -3.0e38f;
    #pragma unroll
    for (int i = 0; i < 10; ++i) { vals[i] = sc[hh][m + 32 * i]; mx = fmaxf(mx, vals[i]); }
    mx = fmaxf(mx, __shfl_xor(mx, 1, 32));
    mx = fmaxf(mx, __shfl_xor(mx, 2, 32));
    mx = fmaxf(mx, __shfl_xor(mx, 4, 32));
    mx = fmaxf(mx, __shfl_xor(mx, 8, 32));
    mx = fmaxf(mx, __shfl_xor(mx, 16, 32));
    float s = 0.f;
    #pragma unroll
    for (int i = 0; i < 10; ++i) { vals[i] = __expf(vals[i] - mx); s += vals[i]; }
    s += __shfl_xor(s, 1, 32);
    s += __shfl_xor(s, 2, 32);
    s += __shfl_xor(s, 4, 32);
    s += __shfl_xor(s, 8, 32);
    s += __shfl_xor(s, 16, 32);
    const float inv = 1.0f / s;
    #pragma unroll
    for (int i = 0; i < 10; ++i) sc[hh][m + 32 * i] = vals[i] * inv;
  }
  __syncthreads();

  // ------- PV -------
  {
    const int d2 = m;   // d = 2*d2
    float2 a0; a0.x = 0.f; a0.y = 0.f;
    float2 a1; a1.x = 0.f; a1.y = 0.f;
    const float* vb = valp + (size_t)b * 320 * 512 + hh * 64 + d2 * 2;
    #pragma unroll 4
    for (int k = 0; k < 320; k += 2) {
      float p0 = sc[hh][k], p1 = sc[hh][k + 1];
      float2 v0 = *reinterpret_cast<const float2*>(vb + (size_t)k * 512);
      float2 v1 = *reinterpret_cast<const float2*>(vb + (size_t)(k + 1) * 512);
      a0.x += p0 * v0.x; a0.y += p0 * v0.y;
      a1.x += p1 * v1.x; a1.y += p1 * v1.y;
    }
    float2 o; o.x = a0.x + a1.x; o.y = a0.y + a1.y;
    *reinterpret_cast<float2*>(out + bq * 512 + hh * 64 + d2 * 2) = o;
  }
}

extern "C" void kernel_launch(void* const* d_in, const int* in_sizes, int n_in,
                              void* d_out, int out_size, void* d_ws, size_t ws_size,
                              hipStream_t stream) {
  const float* query = (const float*)d_in[0];
  const float* key   = (const float*)d_in[1];
  const float* value = (const float*)d_in[2];
  const float* rpe   = (const float*)d_in[3];
  const int*   seq_len = (const int*)d_in[4];
  const int*   lex_num = (const int*)d_in[5];
  const float* Wq = (const float*)d_in[6];
  const float* bq = (const float*)d_in[7];
  const float* Wv = (const float*)d_in[8];
  const float* bv = (const float*)d_in[9];
  const float* Wr = (const float*)d_in[10];
  const float* br = (const float*)d_in[11];
  const float* u  = (const float*)d_in[12];
  const float* v  = (const float*)d_in[13];
  const float* rnd = (const float*)d_in[14];

  float* out = (float*)d_out;
  float* ws = (float*)d_ws;
  float* qu    = ws;                 // 655360 floats
  float* qv    = ws + 655360;        // 655360
  float* valp  = ws + 1310720;       // 655360

  k1_proj<<<dim3(80, 4, 2), 256, 0, stream>>>(query, value, Wq, bq, Wv, bv, u, v, qu, qv, valp);
  k4_attn<<<dim3(320, 4), 256, 0, stream>>>(rpe, key, Wr, br, rnd, seq_len, lex_num, qu, qv, valp, out);
}